// Round 3
// baseline (42.674 us; speedup 1.0000x reference)
//
#include <hip/hip_runtime.h>
#include <hip/hip_cooperative_groups.h>

namespace cg = cooperative_groups;

// Bone/variance loss: B samples -> scalar.
// output: [B,1,64,64] f32, mask: [B,17] f32, ind: [B,17] int32, target: [B,17] f32, gt_2d: [B,17,2] f32
// out: [1] f32
//
// Round 3: single cooperative kernel (128 blocks x 64 threads), grid.sync()
// replaces the second dispatch. Block partials -> d_ws, block 0 finalizes in
// fixed order (deterministic, no float atomics).

#define BLK 64

__global__ __launch_bounds__(BLK) void bone_fused(
    const float* __restrict__ out_hm,
    const float* __restrict__ mask,
    const int*   __restrict__ ind,
    const float* __restrict__ target,
    const float* __restrict__ gt2d,
    float* __restrict__ partial,
    float* __restrict__ out,
    int B, float invB)
{
    constexpr int id1[12]  = {3, 2, 4, 5, 16, 15, 11, 12, 1, 4, 14, 11};
    constexpr int id2[12]  = {2, 1, 5, 6, 15, 14, 12, 13, 0, 0,  8,  8};
    constexpr int gid[12]  = {0, 0, 0, 0,  1,  1,  1,  1, 2, 2,  3,  3};
    const float wbone[12]  = {1.0085885098415446f, 1.0f, 1.0f, 1.0085885098415446f,
                              1.1375361376887123f, 1.0f, 1.0f, 1.1375361376887123f,
                              1.0f, 1.0f, 1.0f, 1.0f};

    const int b = blockIdx.x * BLK + threadIdx.x;
    float per = 0.0f;
    if (b < B) {
        const float*  tb = target + (size_t)b * 17;
        const float*  mb = mask   + (size_t)b * 17;
        const int*    ib = ind    + (size_t)b * 17;
        const float2* gb = (const float2*)(gt2d + (size_t)b * 34);
        const float*  ob = out_hm + (size_t)b * 4096;

        // Issue the long-latency random gathers first (17 independent loads).
        int idx[17];
        #pragma unroll
        for (int j = 0; j < 17; ++j) idx[j] = ib[j];
        float pr[17];
        #pragma unroll
        for (int j = 0; j < 17; ++j) pr[j] = ob[idx[j]];

        float t[17], gx[17], gy[17];
        #pragma unroll
        for (int j = 0; j < 17; ++j) t[j] = tb[j];
        #pragma unroll
        for (int j = 0; j < 17; ++j) { float2 g = gb[j]; gx[j] = g.x; gy[j] = g.y; }
        float msum = 0.0f;
        #pragma unroll
        for (int j = 0; j < 17; ++j) msum += mb[j];

        float num[4] = {0,0,0,0}, sl[4] = {0,0,0,0};
        float l[12];
        bool  vis[12];
        #pragma unroll
        for (int k = 0; k < 12; ++k) {
            const int a = id1[k], c = id2[k];
            const bool v = (t[a] > 0.5f) && (t[c] > 0.5f);
            const float dx = gx[a] - gx[c];
            const float dy = gy[a] - gy[c];
            const float dp = pr[a] - pr[c];
            const float d2 = dx*dx + dy*dy + dp*dp;
            const float lv = v ? sqrtf(d2) * wbone[k] : 0.0f;
            vis[k] = v; l[k] = lv;
            num[gid[k]] += v ? 1.0f : 0.0f;
            sl[gid[k]]  += lv;
        }
        float E[4], dn[4];
        #pragma unroll
        for (int g = 0; g < 4; ++g) { dn[g] = fmaxf(num[g], 1.0f); E[g] = sl[g] / dn[g]; }
        #pragma unroll
        for (int k = 0; k < 12; ++k) {
            if (vis[k] && l[k] > 0.0f) {
                const float d = l[k] - E[gid[k]];
                per += d * d / (2.0f * dn[gid[k]]);
            }
        }
        if (msum != 0.0f) per = 0.0f;   // active = (mask.sum == 0)
    }

    // single-wave block: pure shuffle reduction
    #pragma unroll
    for (int off = 32; off > 0; off >>= 1) per += __shfl_down(per, off, 64);
    if (threadIdx.x == 0) partial[blockIdx.x] = per;

    __threadfence();            // device-scope: make partials visible cross-XCD
    cg::this_grid().sync();

    if (blockIdx.x == 0) {
        float s = 0.0f;
        const int n = gridDim.x;
        for (int i = threadIdx.x; i < n; i += BLK) s += partial[i];
        #pragma unroll
        for (int off = 32; off > 0; off >>= 1) s += __shfl_down(s, off, 64);
        if (threadIdx.x == 0) out[0] = s * invB;   // _VAR_WEIGHT == 1.0
    }
}

extern "C" void kernel_launch(void* const* d_in, const int* in_sizes, int n_in,
                              void* d_out, int out_size, void* d_ws, size_t ws_size,
                              hipStream_t stream)
{
    const float* output = (const float*)d_in[0];
    const float* mask   = (const float*)d_in[1];
    const int*   ind    = (const int*)  d_in[2];
    const float* target = (const float*)d_in[3];
    const float* gt2d   = (const float*)d_in[4];

    int   B    = in_sizes[1] / 17;            // mask is [B,17]
    int   nblk = (B + BLK - 1) / BLK;         // 128 blocks for B=8192
    float invB = 1.0f / (float)B;

    float* partial = (float*)d_ws;            // nblk floats of scratch
    float* outp    = (float*)d_out;

    void* args[] = { (void*)&output, (void*)&mask, (void*)&ind, (void*)&target,
                     (void*)&gt2d, (void*)&partial, (void*)&outp,
                     (void*)&B, (void*)&invB };
    hipLaunchCooperativeKernel((void*)bone_fused, dim3(nblk), dim3(BLK),
                               args, 0, stream);
}

// Round 4
// 11.248 us; speedup vs baseline: 3.7938x; 3.7938x over previous
//
#include <hip/hip_runtime.h>

// Bone/variance loss: B samples -> scalar.
// output: [B,1,64,64] f32, mask: [B,17] f32, ind: [B,17] int32, target: [B,17] f32, gt_2d: [B,17,2] f32
// out: [1] f32
//
// Round 4: bone graph splits into disjoint halves:
//   even lane: joints {0..6}  -> groups 0 (bones (3,2)(2,1)(4,5)(5,6)) and 2 ((1,0)(4,0))
//   odd  lane: joints {8,11..16} -> groups 1 ((16,15)(15,14)(11,12)(12,13)) and 3 ((14,8)(11,8))
// Joints 7,9,10 are unused. 2 lanes/sample -> 7 gathers/lane, 256 blocks (full CU
// coverage). Only cross-lane traffic: one shfl_xor for the mask-sum gate.
// Two plain dispatches (cooperative grid.sync regressed 4x in round 3).

#define BLK 64

__global__ __launch_bounds__(BLK) void bone_partial(
    const float* __restrict__ out_hm,
    const float* __restrict__ mask,
    const int*   __restrict__ ind,
    const float* __restrict__ target,
    const float* __restrict__ gt2d,
    float* __restrict__ partial, int B)
{
    const int tid = blockIdx.x * BLK + threadIdx.x;
    const int p   = tid >> 1;      // sample
    const int h   = tid & 1;       // half
    float per  = 0.0f;
    float msum = 0.0f;

    if (p < B) {
        const float* tb = target + (size_t)p * 17;
        const float* mb = mask   + (size_t)p * 17;
        const int*   ib = ind    + (size_t)p * 17;
        const float* gb = gt2d   + (size_t)p * 34;
        const float* ob = out_hm + (size_t)p * 4096;

        // joint map for this half (compile-time constants selected by h)
        int jm[7];
        jm[0] = h ? 8  : 0;
        jm[1] = h ? 11 : 1;
        jm[2] = h ? 12 : 2;
        jm[3] = h ? 13 : 3;
        jm[4] = h ? 14 : 4;
        jm[5] = h ? 15 : 5;
        jm[6] = h ? 16 : 6;

        // issue index loads, then the long-latency gathers, ASAP
        int idx[7];
        #pragma unroll
        for (int k = 0; k < 7; ++k) idx[k] = ib[jm[k]];
        float pr[7];
        #pragma unroll
        for (int k = 0; k < 7; ++k) pr[k] = ob[idx[k]];

        float t[7], gx[7], gy[7];
        #pragma unroll
        for (int k = 0; k < 7; ++k) t[k] = tb[jm[k]];
        #pragma unroll
        for (int k = 0; k < 7; ++k) {
            float2 g = *(const float2*)(gb + 2 * jm[k]);
            gx[k] = g.x; gy[k] = g.y;
        }

        float numA = 0.f, slA = 0.f, numB = 0.f, slB = 0.f;
        float l[6]; bool vs[6];

        auto bone = [&](int k, int a, int c, float w, bool grpA) {
            const bool v  = (t[a] > 0.5f) && (t[c] > 0.5f);
            const float dx = gx[a] - gx[c];
            const float dy = gy[a] - gy[c];
            const float dp = pr[a] - pr[c];
            const float lv = v ? sqrtf(dx*dx + dy*dy + dp*dp) * w : 0.f;
            vs[k] = v; l[k] = lv;
            if (grpA) { numA += v ? 1.f : 0.f; slA += lv; }
            else      { numB += v ? 1.f : 0.f; slB += lv; }
        };

        if (h == 0) {
            const float W = 1.0085885098415446f;
            bone(0, 3, 2, W,   true);
            bone(1, 2, 1, 1.f, true);
            bone(2, 4, 5, 1.f, true);
            bone(3, 5, 6, W,   true);
            bone(4, 1, 0, 1.f, false);
            bone(5, 4, 0, 1.f, false);
            msum = mb[0]+mb[1]+mb[2]+mb[3]+mb[4]+mb[5]+mb[6]+mb[7]+mb[8];
        } else {
            const float W = 1.1375361376887123f;
            bone(0, 6, 5, W,   true);   // (16,15)
            bone(1, 5, 4, 1.f, true);   // (15,14)
            bone(2, 1, 2, 1.f, true);   // (11,12)
            bone(3, 2, 3, W,   true);   // (12,13)
            bone(4, 4, 0, 1.f, false);  // (14,8)
            bone(5, 1, 0, 1.f, false);  // (11,8)
            msum = mb[9]+mb[10]+mb[11]+mb[12]+mb[13]+mb[14]+mb[15]+mb[16];
        }

        const float dnA = fmaxf(numA, 1.f), EA = slA / dnA;
        const float dnB = fmaxf(numB, 1.f), EB = slB / dnB;
        #pragma unroll
        for (int k = 0; k < 6; ++k) {
            const float E  = (k < 4) ? EA : EB;
            const float dn = (k < 4) ? dnA : dnB;
            if (vs[k] && l[k] > 0.f) {
                const float d = l[k] - E;
                per += d * d / (2.f * dn);
            }
        }
    }

    // mask gate: active = (sum of all 17 mask entries == 0); wave-uniform shfl
    const float mo = __shfl_xor(msum, 1, 64);
    if (msum + mo != 0.0f) per = 0.0f;

    // single-wave block: pure shuffle reduction
    #pragma unroll
    for (int off = 32; off > 0; off >>= 1) per += __shfl_down(per, off, 64);
    if (threadIdx.x == 0) partial[blockIdx.x] = per;
}

__global__ __launch_bounds__(64) void bone_finalize(
    const float* __restrict__ partial, int n,
    float* __restrict__ out, float invB)
{
    float s = 0.0f;
    for (int i = threadIdx.x; i < n; i += 64) s += partial[i];
    #pragma unroll
    for (int off = 32; off > 0; off >>= 1) s += __shfl_down(s, off, 64);
    if (threadIdx.x == 0) out[0] = s * invB;   // _VAR_WEIGHT == 1.0
}

extern "C" void kernel_launch(void* const* d_in, const int* in_sizes, int n_in,
                              void* d_out, int out_size, void* d_ws, size_t ws_size,
                              hipStream_t stream)
{
    const float* output = (const float*)d_in[0];
    const float* mask   = (const float*)d_in[1];
    const int*   ind    = (const int*)  d_in[2];
    const float* target = (const float*)d_in[3];
    const float* gt2d   = (const float*)d_in[4];

    const int B    = in_sizes[1] / 17;           // mask is [B,17]
    const int nblk = (2 * B + BLK - 1) / BLK;    // 256 blocks for B=8192

    float* partial = (float*)d_ws;               // nblk floats of scratch

    bone_partial<<<nblk, BLK, 0, stream>>>(output, mask, ind, target, gt2d, partial, B);
    bone_finalize<<<1, 64, 0, stream>>>(partial, nblk, (float*)d_out, 1.0f / (float)B);
}